// Round 1
// baseline (430.963 us; speedup 1.0000x reference)
//
#include <hip/hip_runtime.h>

#define BATCH 512
#define NNODE 200
#define CIN   200
#define HID   128
#define IPAD  232   // padded i/c length: rows = 464 B -> 16B-aligned, 2-way-only LDS conflicts
#define KCH   7     // 7 K-chunks of 32 (covers 224 >= 200, zero-padded)

typedef __attribute__((ext_vector_type(4))) float  f32x4;
typedef __attribute__((ext_vector_type(8))) short  sh8;
typedef __attribute__((ext_vector_type(4))) short  sh4;
typedef __attribute__((ext_vector_type(8))) __bf16 bf16x8;

__device__ __forceinline__ short f2bf(float x) {
  union { float f; unsigned u; } v; v.f = x;
  unsigned r = v.u + 0x7FFFu + ((v.u >> 16) & 1u);   // RNE
  return (short)(r >> 16);
}
__device__ __forceinline__ float bf2f(short s) {
  union { unsigned u; float f; } v; v.u = ((unsigned)(unsigned short)s) << 16;
  return v.f;
}
__device__ __forceinline__ f32x4 mfma16(sh8 a, sh8 b, f32x4 c) {
  return __builtin_amdgcn_mfma_f32_16x16x32_bf16(
      __builtin_bit_cast(bf16x8, a), __builtin_bit_cast(bf16x8, b), c, 0, 0, 0);
}

// ---------- K0: W1 [200][128] fp32 -> W1T [128][232] bf16 (zero-padded) ----------
__global__ void k_w1t(const float* __restrict__ W1, short* __restrict__ W1T) {
  int e = blockIdx.x * 256 + threadIdx.x;
  if (e >= HID * IPAD) return;
  int f = e / IPAD, c = e % IPAD;
  float v = (c < CIN) ? W1[c * HID + f] : 0.f;
  W1T[e] = f2bf(v);
}

// ---------- K1: per-batch y = x @ W1, output yT[b][f][i] bf16 (i padded to 232, zeroed) ----------
__global__ __launch_bounds__(256) void k_y(const float* __restrict__ x,
                                           const short* __restrict__ W1T,
                                           short* __restrict__ yTws) {
  __shared__ short W1s[HID][IPAD];   // 59,392 B
  const int b = blockIdx.x, tid = threadIdx.x;
  short* yb = yTws + (size_t)b * HID * IPAD;

  { // stage W1T (straight 16B copy)
    const f32x4* src = (const f32x4*)W1T;
    f32x4* dst = (f32x4*)&W1s[0][0];
    for (int i = tid; i < HID * IPAD * 2 / 16; i += 256) dst[i] = src[i];
  }
  { // zero the i in [200,232) pad of this batch's yT (128 rows x 32 shorts)
    for (int i = tid; i < HID * 32 / 4; i += 256) {
      int f = i >> 3, o = (i & 7) * 4;
      *(unsigned long long*)&yb[f * IPAD + NNODE + o] = 0ull;
    }
  }
  __syncthreads();

  const int wave = tid >> 6, lane = tid & 63, lq = lane >> 4, lm = lane & 15;
  const float* xb = x + (size_t)b * NNODE * CIN;

  for (int mt = wave; mt < 13; mt += 4) {          // 13 M-tiles of 16 node-rows
    const int Mbase = mt * 16;
    const int row = Mbase + lm;
    const float* xr = xb + (size_t)min(row, NNODE - 1) * CIN;

    sh8 af[KCH];                                    // A-fragments held across all f-tiles
#pragma unroll
    for (int k = 0; k < KCH; ++k) {
      const int c0 = k * 32 + lq * 8;
      f32x4 p0 = {0.f,0.f,0.f,0.f}, p1 = {0.f,0.f,0.f,0.f};
      if (c0 < CIN) {                               // c0<=192 -> c0+7<=199 in-bounds
        p0 = *(const f32x4*)(xr + c0);
        p1 = *(const f32x4*)(xr + c0 + 4);
      }
      sh8 a;
#pragma unroll
      for (int j = 0; j < 4; ++j) { a[j] = f2bf(p0[j]); a[4 + j] = f2bf(p1[j]); }
      af[k] = a;
    }

    for (int ft = 0; ft < 8; ++ft) {                // 8 N-tiles of 16 features
      const int fb = ft * 16;
      f32x4 acc = {0.f,0.f,0.f,0.f};
#pragma unroll
      for (int k = 0; k < KCH; ++k) {
        sh8 bfr = *(const sh8*)&W1s[fb + lm][k * 32 + lq * 8];
        acc = mfma16(af[k], bfr, acc);
      }
      // C layout: n(col)=lane&15 -> f ; m(row)=lq*4+reg -> i. 4 regs = 4 consecutive i.
      const int i0 = Mbase + lq * 4;
      if (i0 + 3 < NNODE) {
        sh4 st;
#pragma unroll
        for (int r = 0; r < 4; ++r) st[r] = f2bf(acc[r]);
        *(sh4*)&yb[(size_t)(fb + lm) * IPAD + i0] = st;
      }
    }
  }
}

// ---------- K2: per-batch agg1 -> h -> g=h@W2 -> weighted mean ----------
__global__ __launch_bounds__(256) void k_gin2(const short* __restrict__ yTws,
                                              const int* __restrict__ adj,
                                              const float* __restrict__ b1,
                                              const float* __restrict__ W2,
                                              const float* __restrict__ b2,
                                              const float* __restrict__ eps1p,
                                              const float* __restrict__ eps2p,
                                              float* __restrict__ out) {
  __shared__ short yT[HID][IPAD];   // 59,392 B
  __shared__ float g2[NNODE][2];    // 1,600 B
  __shared__ int   rowdeg[IPAD];    // 928 B
  __shared__ float b1s[HID];        // 512 B
  __shared__ float W2s[HID][2];     // 1,024 B
  __shared__ float red[8];
  const int b = blockIdx.x, tid = threadIdx.x;

  { // stage yT
    const f32x4* src = (const f32x4*)(yTws + (size_t)b * HID * IPAD);
    f32x4* dst = (f32x4*)&yT[0][0];
    for (int i = tid; i < HID * IPAD * 2 / 16; i += 256) dst[i] = src[i];
  }
  if (tid < IPAD) rowdeg[tid] = 0;
  if (tid < HID) { b1s[tid] = b1[tid]; W2s[tid][0] = W2[tid * 2]; W2s[tid][1] = W2[tid * 2 + 1]; }
  const float e1 = 1.f + eps1p[0];
  const float e2 = 1.f + eps2p[0];
  __syncthreads();

  const int wave = tid >> 6, lane = tid & 63, lq = lane >> 4, lm = lane & 15;
  const int* adjb = adj + (size_t)b * NNODE * NNODE;

  for (int jt = wave; jt < 13; jt += 4) {           // 13 j-tiles of 16 output nodes
    const int jbase = jt * 16;
    const int j = jbase + lm;
    const bool jok = (j < NNODE);
    const int jc = min(j, NNODE - 1);

    // B-fragments (adjacency column tile, 0/1 -> bf16) + rowdeg butterfly
    sh8 bf[KCH];
#pragma unroll
    for (int k = 0; k < KCH; ++k) {
      sh8 frag;
#pragma unroll
      for (int r = 0; r < 8; ++r) {
        const int i = k * 32 + lq * 8 + r;
        int ival = (i < NNODE) ? adjb[i * NNODE + jc] : 0;
        int v = jok ? ival : 0;
        frag[r] = v ? (short)0x3F80 : (short)0;
        int cnt = v;                                 // rowdeg_i += sum over 16 j's
        cnt += __shfl_xor(cnt, 1);
        cnt += __shfl_xor(cnt, 2);
        cnt += __shfl_xor(cnt, 4);
        cnt += __shfl_xor(cnt, 8);
        if (lm == 0 && i < NNODE) atomicAdd(&rowdeg[i], cnt);
      }
      bf[k] = frag;
    }

    float ga = 0.f, gb = 0.f;                        // g[j][0..1] partials (lane's j fixed)
    for (int ft = 0; ft < 8; ++ft) {
      const int fb2 = ft * 16;
      f32x4 acc = {0.f,0.f,0.f,0.f};
#pragma unroll
      for (int k = 0; k < KCH; ++k) {
        sh8 afr = *(const sh8*)&yT[fb2 + lm][k * 32 + lq * 8];
        acc = mfma16(afr, bf[k], acc);               // D[m=f][n=j] = sum_i yT[f][i]*A[i][j]
      }
#pragma unroll
      for (int r = 0; r < 4; ++r) {
        const int f = fb2 + lq * 4 + r;
        const float yself = bf2f(yT[f][jc]);
        float h = e1 * yself + acc[r] + b1s[f];
        h = fmaxf(h, 0.f);
        ga += h * W2s[f][0];
        gb += h * W2s[f][1];
      }
    }
    ga += __shfl_xor(ga, 16); ga += __shfl_xor(ga, 32);
    gb += __shfl_xor(gb, 16); gb += __shfl_xor(gb, 32);
    if (lane < 16 && jok) { g2[j][0] = ga; g2[j][1] = gb; }
  }
  __syncthreads();

  // out[b] = b2 + (1/N) * sum_i (1+eps2 + rowdeg[i]) * g[i]
  float v0 = 0.f, v1 = 0.f;
  if (tid < NNODE) {
    const float w = e2 + (float)rowdeg[tid];
    v0 = w * g2[tid][0];
    v1 = w * g2[tid][1];
  }
#pragma unroll
  for (int d = 1; d < 64; d <<= 1) { v0 += __shfl_xor(v0, d); v1 += __shfl_xor(v1, d); }
  if (lane == 0) { red[wave * 2] = v0; red[wave * 2 + 1] = v1; }
  __syncthreads();
  if (tid == 0) {
    const float s0 = red[0] + red[2] + red[4] + red[6];
    const float s1 = red[1] + red[3] + red[5] + red[7];
    out[b * 2 + 0] = b2[0] + s0 * (1.f / NNODE);
    out[b * 2 + 1] = b2[1] + s1 * (1.f / NNODE);
  }
}

extern "C" void kernel_launch(void* const* d_in, const int* in_sizes, int n_in,
                              void* d_out, int out_size, void* d_ws, size_t ws_size,
                              hipStream_t stream) {
  const float* x    = (const float*)d_in[0];
  const int*   adj  = (const int*)d_in[1];
  const float* W1   = (const float*)d_in[2];
  const float* b1   = (const float*)d_in[3];
  const float* W2   = (const float*)d_in[4];
  const float* b2   = (const float*)d_in[5];
  const float* eps1 = (const float*)d_in[6];
  const float* eps2 = (const float*)d_in[7];
  float* out = (float*)d_out;

  short* W1T = (short*)d_ws;                       // [128][232] bf16
  short* yT  = (short*)d_ws + HID * IPAD;          // [512][128][232] bf16 (~30 MB)

  k_w1t <<<(HID * IPAD + 255) / 256, 256, 0, stream>>>(W1, W1T);
  k_y   <<<BATCH, 256, 0, stream>>>(x, W1T, yT);
  k_gin2<<<BATCH, 256, 0, stream>>>(yT, adj, b1, W2, b2, eps1, eps2, out);
}

// Round 2
// 338.142 us; speedup vs baseline: 1.2745x; 1.2745x over previous
//
#include <hip/hip_runtime.h>

#define BATCH 512
#define NNODE 200
#define CIN   200
#define HID   128
#define IPAD  224   // padded contraction length: 7 chunks of 32
#define KCH   7

typedef __attribute__((ext_vector_type(4))) float  f32x4;
typedef __attribute__((ext_vector_type(8))) short  sh8;
typedef __attribute__((ext_vector_type(4))) short  sh4;
typedef __attribute__((ext_vector_type(8))) __bf16 bf16x8;

__device__ __forceinline__ short f2bf(float x) {
  union { float f; unsigned u; } v; v.f = x;
  unsigned r = v.u + 0x7FFFu + ((v.u >> 16) & 1u);   // RNE
  return (short)(r >> 16);
}
__device__ __forceinline__ f32x4 mfma16(sh8 a, sh8 b, f32x4 c) {
  return __builtin_amdgcn_mfma_f32_16x16x32_bf16(
      __builtin_bit_cast(bf16x8, a), __builtin_bit_cast(bf16x8, b), c, 0, 0, 0);
}

// ---------- K0: W1 [200][128] fp32 -> W1T [128][224] bf16 (cols [200,224) zeroed) ----------
__global__ void k_w1t(const float* __restrict__ W1, short* __restrict__ W1T) {
  int idx = blockIdx.x * 256 + threadIdx.x;
  if (idx < CIN * HID) {                       // coalesced read of W1
    int c = idx >> 7, f = idx & 127;
    W1T[f * IPAD + c] = f2bf(W1[idx]);
  } else {
    int q = idx - CIN * HID;                   // zero pad cols
    if (q < HID * (IPAD - CIN)) {
      int f = q / (IPAD - CIN), c = CIN + q % (IPAD - CIN);
      W1T[f * IPAD + c] = 0;
    }
  }
}

// ---------- K_adjT: adj int [b][i][j] -> bf16 adjT[b][j][i] with (1+eps1) on diagonal ----------
// grid: (b, jstrip of 50) = 512*4 blocks, 256 threads. LDS tile [50][232] (decoupled stride).
__global__ __launch_bounds__(256) void k_adjT(const int* __restrict__ adj,
                                              const float* __restrict__ eps1p,
                                              short* __restrict__ adjT) {
  __shared__ short tile[50][232];
  const int b = blockIdx.x >> 2, s = blockIdx.x & 3, tid = threadIdx.x;
  const int* adjb = adj + (size_t)b * NNODE * NNODE;
  const float onepe1 = 1.f + eps1p[0];

  // zero tile cols [200,224)
  for (int idx = tid; idx < 50 * 12; idx += 256) {
    int r = idx / 12, c = idx % 12;
    *(int*)&tile[r][200 + 2 * c] = 0;
  }

  const int di = tid >> 6, dj = tid & 63;      // wave w reads row i0+w, lanes = j
  const int jg = s * 50 + dj;
  if (dj < 50) {
    for (int i0 = 0; i0 < NNODE; i0 += 4) {
      const int i = i0 + di;
      int ival = adjb[i * NNODE + jg];
      float v = (float)ival + (jg == i ? onepe1 : 0.f);
      tile[dj][i] = f2bf(v);
    }
  }
  __syncthreads();

  short* adjTb = adjT + (size_t)b * NNODE * IPAD;
  for (int idx = tid; idx < 50 * 28; idx += 256) {   // 16B stores, row-coalesced
    int r = idx / 28, off = (idx % 28) * 8;
    *(sh8*)&adjTb[(size_t)(s * 50 + r) * IPAD + off] = *(const sh8*)&tile[r][off];
  }
}

// ---------- K1: y = x @ W1 -> yT[b][f][i] bf16. One wave per (b, mt). No LDS. ----------
__global__ __launch_bounds__(256) void k_y(const float* __restrict__ x,
                                           const short* __restrict__ W1T,
                                           short* __restrict__ yTws) {
  const int wave = threadIdx.x >> 6, lane = threadIdx.x & 63;
  const int wid = blockIdx.x * 4 + wave;       // 0..6655
  const int b = wid / 13, mt = wid - b * 13;
  const int lq = lane >> 4, lm = lane & 15;

  const float* xb = x + (size_t)b * NNODE * CIN;
  short* yb = yTws + (size_t)b * HID * IPAD;
  const int Mbase = mt * 16;
  const int row = min(Mbase + lm, NNODE - 1);
  const float* xr = xb + (size_t)row * CIN;

  sh8 af[KCH];                                  // A-fragments (x rows), kept across f-tiles
#pragma unroll
  for (int k = 0; k < KCH; ++k) {
    const int c0 = k * 32 + lq * 8;
    f32x4 p0 = {0.f,0.f,0.f,0.f}, p1 = {0.f,0.f,0.f,0.f};
    if (c0 < CIN) { p0 = *(const f32x4*)(xr + c0); p1 = *(const f32x4*)(xr + c0 + 4); }
    sh8 a;
#pragma unroll
    for (int j = 0; j < 4; ++j) { a[j] = f2bf(p0[j]); a[4 + j] = f2bf(p1[j]); }
    af[k] = a;
  }

  for (int ft = 0; ft < 8; ++ft) {
    const int fb = ft * 16;
    const short* wrow = W1T + (size_t)(fb + lm) * IPAD;   // B[k=c][n=f=fb+lm]
    f32x4 acc = {0.f,0.f,0.f,0.f};
#pragma unroll
    for (int k = 0; k < KCH; ++k)
      acc = mfma16(af[k], *(const sh8*)(wrow + k * 32 + lq * 8), acc);
    // D: n=lm -> f; m=lq*4+r -> i. Unconditional store (i in [200,208) junk * adjT zeros).
    sh4 st;
#pragma unroll
    for (int r = 0; r < 4; ++r) st[r] = f2bf(acc[r]);
    *(sh4*)&yb[(size_t)(fb + lm) * IPAD + Mbase + lq * 4] = st;
  }
}

// ---------- K2: per-batch two-pass. 512 threads (8 waves), one wave per j-tile. ----------
// pass1: D[f][j] = sum_i yT[f][i]*adjT'[i][j]  -> h=relu(D+b1) -> g[j] = h@W2 (fp32)
// pass2: D2[c][j] = sum_i g[i][c]*adjT'[i][j]; out = b2 + (sumagg + (e2-e1)*sumg)/N
__global__ __launch_bounds__(512) void k_gin2(const short* __restrict__ yTws,
                                              const short* __restrict__ adjT,
                                              const float* __restrict__ b1,
                                              const float* __restrict__ W2,
                                              const float* __restrict__ b2,
                                              const float* __restrict__ eps1p,
                                              const float* __restrict__ eps2p,
                                              float* __restrict__ out) {
  __shared__ short gT[16][IPAD];               // rows 0,1 = g; rows 2..15 zero
  __shared__ float b1s[HID], W2s[HID][2];
  __shared__ float sumg[2], sumagg[2];
  const int b = blockIdx.x, tid = threadIdx.x;
  const int wave = tid >> 6, lane = tid & 63, lq = lane >> 4, lm = lane & 15;

  for (int i = tid; i < 16 * IPAD / 2; i += 512) ((int*)gT)[i] = 0;
  if (tid < HID) { b1s[tid] = b1[tid]; W2s[tid][0] = W2[tid * 2]; W2s[tid][1] = W2[tid * 2 + 1]; }
  if (tid < 2) { sumg[tid] = 0.f; sumagg[tid] = 0.f; }
  const float e1 = eps1p[0], e2 = eps2p[0];
  __syncthreads();

  const short* yb = yTws + (size_t)b * HID * IPAD;
  const short* adjTb = adjT + (size_t)b * NNODE * IPAD;

  // ---- pass 1 ----
  for (int jt = wave; jt < 13; jt += 8) {
    const int j = jt * 16 + lm;
    const bool jok = (j < NNODE);
    const short* arow = adjTb + (size_t)min(j, NNODE - 1) * IPAD;

    sh8 bf[KCH];                                // B[k=i][n=j]: 16B contiguous loads
#pragma unroll
    for (int k = 0; k < KCH; ++k) bf[k] = *(const sh8*)(arow + k * 32 + lq * 8);

    float ga = 0.f, gb = 0.f;
    for (int ft = 0; ft < 8; ++ft) {
      const int fb2 = ft * 16;
      const short* yrow = yb + (size_t)(fb2 + lm) * IPAD;
      f32x4 acc = {0.f,0.f,0.f,0.f};
#pragma unroll
      for (int k = 0; k < KCH; ++k)
        acc = mfma16(*(const sh8*)(yrow + k * 32 + lq * 8), bf[k], acc);
#pragma unroll
      for (int r = 0; r < 4; ++r) {
        const int f = fb2 + lq * 4 + r;         // D[m=f][n=j], diag already has (1+e1)*y
        float h = fmaxf(acc[r] + b1s[f], 0.f);
        ga += h * W2s[f][0];
        gb += h * W2s[f][1];
      }
    }
    ga += __shfl_xor(ga, 16); ga += __shfl_xor(ga, 32);   // sum 4 lq groups -> full f-sum
    gb += __shfl_xor(gb, 16); gb += __shfl_xor(gb, 32);
    if (lane < 16 && jok) { gT[0][j] = f2bf(ga); gT[1][j] = f2bf(gb); }
    float ta = (lane < 16 && jok) ? ga : 0.f;
    float tb = (lane < 16 && jok) ? gb : 0.f;
#pragma unroll
    for (int d = 1; d < 16; d <<= 1) { ta += __shfl_xor(ta, d); tb += __shfl_xor(tb, d); }
    if (lane == 0) { atomicAdd(&sumg[0], ta); atomicAdd(&sumg[1], tb); }
  }
  __syncthreads();

  // ---- pass 2: agg2' = adjT'^T g ----
  for (int jt = wave; jt < 13; jt += 8) {
    const int j = jt * 16 + lm;
    const bool jok = (j < NNODE);
    const short* arow = adjTb + (size_t)min(j, NNODE - 1) * IPAD;
    f32x4 acc = {0.f,0.f,0.f,0.f};
#pragma unroll
    for (int k = 0; k < KCH; ++k) {
      sh8 gfrag = *(const sh8*)&gT[lm][k * 32 + lq * 8];  // A[m=c][k=i], rows>=2 zero
      acc = mfma16(gfrag, *(const sh8*)(arow + k * 32 + lq * 8), acc);
    }
    float v0 = (lq == 0 && jok) ? acc[0] : 0.f;           // D2[c=r][j=lm] at lq==0
    float v1 = (lq == 0 && jok) ? acc[1] : 0.f;
#pragma unroll
    for (int d = 1; d < 16; d <<= 1) { v0 += __shfl_xor(v0, d); v1 += __shfl_xor(v1, d); }
    if (lane == 0) { atomicAdd(&sumagg[0], v0); atomicAdd(&sumagg[1], v1); }
  }
  __syncthreads();

  if (tid == 0) {
    // sumagg = sum_j agg2 + (1+e1)*sumg ; need sum_j[(1+e2)g + agg2] = sumagg + (e2-e1)*sumg
    out[b * 2 + 0] = b2[0] + (sumagg[0] + (e2 - e1) * sumg[0]) * (1.f / NNODE);
    out[b * 2 + 1] = b2[1] + (sumagg[1] + (e2 - e1) * sumg[1]) * (1.f / NNODE);
  }
}

extern "C" void kernel_launch(void* const* d_in, const int* in_sizes, int n_in,
                              void* d_out, int out_size, void* d_ws, size_t ws_size,
                              hipStream_t stream) {
  const float* x    = (const float*)d_in[0];
  const int*   adj  = (const int*)d_in[1];
  const float* W1   = (const float*)d_in[2];
  const float* b1   = (const float*)d_in[3];
  const float* W2   = (const float*)d_in[4];
  const float* b2   = (const float*)d_in[5];
  const float* eps1 = (const float*)d_in[6];
  const float* eps2 = (const float*)d_in[7];
  float* out = (float*)d_out;

  short* W1T  = (short*)d_ws;                                    // [128][224]
  short* adjT = W1T + HID * IPAD;                                // [512][200][224] (~45.9 MB)
  short* yT   = adjT + (size_t)BATCH * NNODE * IPAD;             // [512][128][224] (~29.4 MB)

  k_w1t <<<(HID * IPAD + 255) / 256, 256, 0, stream>>>(W1, W1T);
  k_adjT<<<BATCH * 4, 256, 0, stream>>>(adj, eps1, adjT);
  k_y   <<<(BATCH * 13) / 4, 256, 0, stream>>>(x, W1T, yT);
  k_gin2<<<BATCH, 512, 0, stream>>>(yT, adjT, b1, W2, b2, eps1, eps2, out);
}